// Round 3
// baseline (101.730 us; speedup 1.0000x reference)
//
#include <hip/hip_runtime.h>
#include <hip/hip_bf16.h>
#include <math.h>

#define N 256
#define D 512
#define C 16
#define NBINS 1000
#define MCELL 1000
#define CPB 125          // cells per k_conv block (8 blocks/mat)
#define EPSF 1e-9f
// -50/ln(2): exp(-50*q^2) = exp2(KEXP2*q^2)
#define KEXP2 -72.134752f

__device__ inline float waveReduceSum(float v) {
#pragma unroll
    for (int off = 32; off > 0; off >>= 1) v += __shfl_down(v, off, 64);
    return v;
}
__device__ inline double waveReduceSumD(double v) {
#pragma unroll
    for (int off = 32; off > 0; off >>= 1) v += __shfl_down(v, off, 64);
    return v;
}

// L2-normalize rows of T and S -> xn (row major) and xnT (transposed).
// Fused: lab[i] = argmax_c labels[i,c] (first-max).
__global__ void k_norm(const float* __restrict__ T, const float* __restrict__ S,
                       const float* __restrict__ labels,
                       float* __restrict__ xn, float* __restrict__ xnT,
                       int* __restrict__ lab) {
    int i = blockIdx.x;
    int mat = blockIdx.y;
    const float* in = mat ? S : T;
    int tid = threadIdx.x;  // 256 threads, row has 512 elems
    if (mat == 0 && tid == 0) {
        float best = labels[i * C];
        int bi = 0;
#pragma unroll
        for (int c = 1; c < C; ++c) {
            float v = labels[i * C + c];
            if (v > best) { best = v; bi = c; }
        }
        lab[i] = bi;
    }
    float v0 = in[i * D + tid];
    float v1 = in[i * D + 256 + tid];
    float ss = v0 * v0 + v1 * v1;
    ss = waveReduceSum(ss);
    __shared__ float lds[4];
    __shared__ float inv_s;
    int wid = tid >> 6, lane = tid & 63;
    if (lane == 0) lds[wid] = ss;
    __syncthreads();
    if (tid == 0) {
        float tot = lds[0] + lds[1] + lds[2] + lds[3];
        inv_s = 1.0f / fmaxf(sqrtf(tot), 1e-12f);
    }
    __syncthreads();
    float inv = inv_s;
    float* xnm = xn + mat * (N * D);
    float* xnTm = xnT + mat * (N * D);
    float a = v0 * inv, b = v1 * inv;
    xnm[i * D + tid] = a;
    xnm[i * D + 256 + tid] = b;
    xnTm[tid * N + i] = a;
    xnTm[(tid + 256) * N + i] = b;
}

// cos rows + classify + pack (d, wp). Block = 4 rows x 256 cols. Diag flagged d=9.
__global__ void __launch_bounds__(256) k_cos(
        const float* __restrict__ xn, const float* __restrict__ xnT,
        const int* __restrict__ lab, float2* __restrict__ c2) {
    int mat = blockIdx.y;
    int i0 = blockIdx.x * 4;
    int j = threadIdx.x;  // 256
    const float* xnm = xn + mat * (N * D);
    const float* xc = xnT + mat * (N * D);
    __shared__ float rows[D][4];  // [k][r], 16B rows -> float4 broadcast reads
#pragma unroll
    for (int r = 0; r < 4; ++r) {
        rows[j][r] = xnm[(i0 + r) * D + j];
        rows[j + 256][r] = xnm[(i0 + r) * D + 256 + j];
    }
    int labj = lab[j];
    int li0 = lab[i0], li1 = lab[i0 + 1], li2 = lab[i0 + 2], li3 = lab[i0 + 3];
    __syncthreads();

    float a0 = 0.f, a1 = 0.f, a2 = 0.f, a3 = 0.f;
#pragma unroll 8
    for (int k = 0; k < D; ++k) {
        float xb = xc[k * N + j];                       // coalesced
        float4 rr = *(const float4*)&rows[k][0];        // wave-uniform broadcast
        a0 = fmaf(rr.x, xb, a0);
        a1 = fmaf(rr.y, xb, a1);
        a2 = fmaf(rr.z, xb, a2);
        a3 = fmaf(rr.w, xb, a3);
    }
    float2* cm = c2 + mat * (N * N);
    float wp0 = (labj == li0 && j != i0) ? 1.f : 0.f;
    float wp1 = (labj == li1 && j != i0 + 1) ? 1.f : 0.f;
    float wp2 = (labj == li2 && j != i0 + 2) ? 1.f : 0.f;
    float wp3 = (labj == li3 && j != i0 + 3) ? 1.f : 0.f;
    cm[(i0 + 0) * N + j] = make_float2((j == i0 + 0) ? 9.0f : a0, wp0);
    cm[(i0 + 1) * N + j] = make_float2((j == i0 + 1) ? 9.0f : a1, wp1);
    cm[(i0 + 2) * N + j] = make_float2((j == i0 + 2) ? 9.0f : a2, wp2);
    cm[(i0 + 3) * N + j] = make_float2((j == i0 + 3) ? 9.0f : a3, wp3);
}

// Moments per fine cell (m0,m1,m2 for all-nondiag and pos) + row E-means.
// Block = 8192 dists = 32 complete rows. LDS partial moments, one global merge.
__global__ void __launch_bounds__(1024) k_moments(const float2* __restrict__ c2,
        float* __restrict__ mg, float* __restrict__ Earr, float* __restrict__ cpos) {
    int mat = blockIdx.y;
    int tid = threadIdx.x;
    __shared__ float mom[6][MCELL];
    __shared__ float rowacc[3][32];
    for (int i = tid; i < 6 * MCELL; i += 1024) (&mom[0][0])[i] = 0.f;
    if (tid < 96) (&rowacc[0][0])[tid] = 0.f;
    __syncthreads();
    int base = blockIdx.x * 8192;
    int lane = tid & 63;
#pragma unroll
    for (int it = 0; it < 8; ++it) {
        int li = it * 1024 + tid;
        float2 v = c2[mat * (N * N) + base + li];
        float d = v.x, wp = v.y;
        bool valid = (d < 8.f);  // diag flagged 9
        if (valid) {
            int j = (int)floorf((d + 1.f) * 500.f);
            j = min(max(j, 0), MCELL - 1);
            float cc = -1.f + ((float)j + 0.5f) * 0.002f;
            float del = d - cc;
            float dd = del * del;
            atomicAdd(&mom[0][j], 1.f);
            atomicAdd(&mom[1][j], del);
            atomicAdd(&mom[2][j], dd);
            if (wp > 0.f) {
                atomicAdd(&mom[3][j], 1.f);
                atomicAdd(&mom[4][j], del);
                atomicAdd(&mom[5][j], dd);
            }
        }
        // row partial sums; 64 consecutive idx stay in one row (256 | rows)
        float sA = valid ? d : 0.f;
        float sP = valid ? d * wp : 0.f;
        float cP = valid ? wp : 0.f;
        sA = waveReduceSum(sA);
        sP = waveReduceSum(sP);
        cP = waveReduceSum(cP);
        if (lane == 0) {
            int row = li >> 8;  // 0..31 local
            atomicAdd(&rowacc[0][row], sA);
            atomicAdd(&rowacc[1][row], sP);
            atomicAdd(&rowacc[2][row], cP);
        }
    }
    __syncthreads();
    for (int i = tid; i < 6 * MCELL; i += 1024)
        atomicAdd(&mg[mat * 6 * MCELL + i], (&mom[0][0])[i]);
    if (tid < 32) {
        int row = blockIdx.x * 32 + tid;
        float sA = rowacc[0][tid], sP = rowacc[1][tid], cP = rowacc[2][tid];
        Earr[(mat * 2 + 0) * N + row] = sP / cP;
        Earr[(mat * 2 + 1) * N + row] = (sA - sP) / (255.f - cP);
        if (mat == 0) cpos[row] = cP;
    }
}

// Convolution of cell moments with the Gaussian: thread = bin, loop over cells.
// e(d,t) ~= E(q) * (m0 - 100q*m1 + (5000q^2-50)*m2), q = cell_center - t
__global__ void __launch_bounds__(1024) k_conv(const float* __restrict__ mg,
        float* __restrict__ hp, float* __restrict__ hs) {
    int mat = blockIdx.y;
    int tid = threadIdx.x;
    int c0 = blockIdx.x * CPB;
    __shared__ float sm[6][CPB];
    if (tid < 6 * CPB) {
        int m = tid / CPB, j = tid - m * CPB;
        sm[m][j] = mg[mat * 6 * MCELL + m * MCELL + c0 + j];
    }
    __syncthreads();
    float tb = -1.f + 0.002f * (float)tid;  // bin left edge t_k = -1 + 0.002k
    float pa = 0.f, sa = 0.f;
    for (int jj = 0; jj < CPB; ++jj) {
        float m0a = sm[0][jj];
        if (m0a == 0.f) continue;  // wave-uniform skip of empty cells
        float cj = -1.f + ((float)(c0 + jj) + 0.5f) * 0.002f;
        float q = cj - tb;
        float q2 = q * q;
        if (q2 < 0.5f) {  // exp(-50*0.5) ~ 1.4e-11: negligible beyond
            float E = __builtin_amdgcn_exp2f(KEXP2 * q2);
            float u = 100.f * q;
            float w2 = fmaf(0.5f * u, u, -50.f);
            sa = fmaf(E, fmaf(w2, sm[2][jj], fmaf(-u, sm[1][jj], m0a)), sa);
            pa = fmaf(E, fmaf(w2, sm[5][jj], fmaf(-u, sm[4][jj], sm[3][jj])), pa);
        }
    }
    if (tid < NBINS) {
        atomicAdd(&hp[mat * NBINS + tid], pa);
        atomicAdd(&hs[mat * NBINS + tid], sa);
    }
}

// final: counts from cpos, KLs over bins + order terms over rows (double accum)
__global__ void __launch_bounds__(1024) k_final(const float* __restrict__ hp,
                                                const float* __restrict__ hs,
                                                const float* __restrict__ Earr,
                                                const float* __restrict__ cpos,
                                                float* __restrict__ out) {
    int tid = threadIdx.x;
    int wid = tid >> 6, lane = tid & 63;
    __shared__ float cred[16];
    __shared__ float pcnt_s;
    float cv = (tid < N) ? cpos[tid] : 0.f;
    cv = waveReduceSum(cv);
    if (lane == 0) cred[wid] = cv;
    __syncthreads();
    if (tid == 0) {
        float t = 0;
        for (int w = 0; w < 16; ++w) t += cred[w];
        pcnt_s = t;
    }
    __syncthreads();
    float pcnt = pcnt_s;
    float ncnt = 65280.f - pcnt;  // N*N - N - pcnt

    double poskl = 0, negkl = 0, o1 = 0, o2 = 0, o3 = 0;
    if (tid < NBINS) {
        float hpT = hp[0 * NBINS + tid], hsT = hs[0 * NBINS + tid];
        float hpS = hp[1 * NBINS + tid], hsS = hs[1 * NBINS + tid];
        float pt = hpT / pcnt;
        float nt = (hsT - hpT) / ncnt;
        float ps = hpS / pcnt;
        float ns = (hsS - hpS) / ncnt;
        poskl = (double)((pt + EPSF) * (__logf(pt + EPSF) - __logf(ps + EPSF)));
        negkl = (double)((nt + EPSF) * (__logf(nt + EPSF) - __logf(ns + EPSF)));
    }
    if (tid < N) {
        float ept = Earr[0 * N + tid];
        float ent = Earr[1 * N + tid];
        float eps_ = Earr[2 * N + tid];
        float ens = Earr[3 * N + tid];
        o1 = fabs((double)ept - (double)eps_);
        o2 = fabs((double)ent - (double)ens);
        o3 = (double)eps_ - (double)ens;
    }
    poskl = waveReduceSumD(poskl);
    negkl = waveReduceSumD(negkl);
    o1 = waveReduceSumD(o1);
    o2 = waveReduceSumD(o2);
    o3 = waveReduceSumD(o3);
    __shared__ double lds[16][5];
    if (lane == 0) {
        lds[wid][0] = poskl; lds[wid][1] = negkl;
        lds[wid][2] = o1; lds[wid][3] = o2; lds[wid][4] = o3;
    }
    __syncthreads();
    if (tid == 0) {
        double a = 0, b = 0, c = 0, d = 0, e = 0;
        for (int w = 0; w < 16; ++w) {
            a += lds[w][0]; b += lds[w][1]; c += lds[w][2]; d += lds[w][3]; e += lds[w][4];
        }
        double loss = 0.1 * a + 0.02 * b + 0.5 * ((c + d + e) / (double)N);
        out[0] = (float)loss;
    }
}

extern "C" void kernel_launch(void* const* d_in, const int* in_sizes, int n_in,
                              void* d_out, int out_size, void* d_ws, size_t ws_size,
                              hipStream_t stream) {
    const float* T = (const float*)d_in[0];
    const float* S = (const float*)d_in[1];
    const float* labels = (const float*)d_in[2];
    float* out = (float*)d_out;

    float* ws = (float*)d_ws;
    float* xn = ws;                            // 2*N*D = 262144
    float* xnT = xn + 2 * N * D;               // 262144
    float2* c2 = (float2*)(xnT + 2 * N * D);   // 2*N*N float2 = 262144 floats
    float* mg = (float*)(c2 + 2 * N * N);      // 2*6*MCELL = 12000
    float* hp = mg + 2 * 6 * MCELL;            // 2*NBINS
    float* hs = hp + 2 * NBINS;                // 2*NBINS
    float* Earr = hs + 2 * NBINS;              // 4*N
    float* cpos = Earr + 4 * N;                // N
    int* lab = (int*)(cpos + N);               // N ints

    // zero the atomically-accumulated regions: mg + hp + hs (contiguous)
    hipMemsetAsync(mg, 0, (size_t)(2 * 6 * MCELL + 4 * NBINS) * sizeof(float), stream);

    k_norm<<<dim3(N, 2), 256, 0, stream>>>(T, S, labels, xn, xnT, lab);
    k_cos<<<dim3(N / 4, 2), 256, 0, stream>>>(xn, xnT, lab, c2);
    k_moments<<<dim3(8, 2), 1024, 0, stream>>>(c2, mg, Earr, cpos);
    k_conv<<<dim3(8, 2), 1024, 0, stream>>>(mg, hp, hs);
    k_final<<<1, 1024, 0, stream>>>(hp, hs, Earr, cpos, out);
}